// Round 6
// baseline (450.759 us; speedup 1.0000x reference)
//
#include <hip/hip_runtime.h>
#include <hip/hip_bf16.h>
#include <cstdint>

// Problem constants: B=4, S=2048, D=1024, H=16, HD=64
static constexpr int Bq  = 4;
static constexpr int Sq  = 2048;
static constexpr int Dq  = 1024;
static constexpr int Hq  = 16;
static constexpr int HDq = 64;
static constexpr int ROWS = Bq * Sq;        // 8192
static constexpr int QKV_N = 3 * Dq;        // 3072
static constexpr int VP   = 2112;           // Vt pitch (el): 4224 B = 33 lines, non-pow2

typedef __bf16 bf16x8 __attribute__((ext_vector_type(8)));
typedef __bf16 bf16x4 __attribute__((ext_vector_type(4)));
typedef float  floatx4 __attribute__((ext_vector_type(4)));

#define MFMA16(a, b, c) __builtin_amdgcn_mfma_f32_16x16x32_bf16((a), (b), (c), 0, 0, 0)

// 0.125 (1/sqrt(HD)) * log2(e): folded into q so softmax uses exp2 directly.
#define QSCALE 0.18033688011112042f

// Async global->LDS 16B copy (global_load_lds_dwordx4).
__device__ __forceinline__ void async16(const void* g, void* l) {
    __builtin_amdgcn_global_load_lds(
        (const __attribute__((address_space(1))) uint32_t*)g,
        (__attribute__((address_space(3))) uint32_t*)l, 16, 0, 0);
}

// ---------------------------------------------------------------------------
// fp32 -> bf16 elementwise convert, 4 elems/thread
__global__ __launch_bounds__(256) void cvt4_kernel(const float4* __restrict__ in,
                                                   bf16x4* __restrict__ out, int n4) {
    int i = blockIdx.x * 256 + threadIdx.x;
    if (i < n4) {
        float4 v = in[i];
        bf16x4 o;
        o[0] = (__bf16)v.x; o[1] = (__bf16)v.y; o[2] = (__bf16)v.z; o[3] = (__bf16)v.w;
        out[i] = o;
    }
}

// fp32 [K,N] -> bf16 transposed [N,K], LDS-tiled 32x32 for coalescing
__global__ __launch_bounds__(256) void tcvt_kernel(const float* __restrict__ in,
                                                   __bf16* __restrict__ out, int K, int N) {
    __shared__ float t[32][33];
    int n0 = blockIdx.x * 32, k0 = blockIdx.y * 32;
    int c = threadIdx.x & 31, r0 = threadIdx.x >> 5;
#pragma unroll
    for (int rr = 0; rr < 32; rr += 8)
        t[r0 + rr][c] = in[(size_t)(k0 + r0 + rr) * N + n0 + c];
    __syncthreads();
#pragma unroll
    for (int rr = 0; rr < 32; rr += 8)
        out[(size_t)(n0 + r0 + rr) * K + k0 + c] = (__bf16)t[c][r0 + rr];
}

// ---------------------------------------------------------------------------
// C[M,N] = A[M,K] @ BT[N,K]^T + bias[N]  (m97-ladder structure).
// MODE 1: f32 C out.  MODE 2 (QKV): q-chunks scaled by QSCALE -> bf16 C;
// k-chunks -> bf16 C; v-chunks -> transposed Vt[b][h][d][s] with pitch VP.
template <int MODE>
__global__ __launch_bounds__(256) void gemm_bt_kernel(const __bf16* __restrict__ A,
                                                      const __bf16* __restrict__ BT,
                                                      const float* __restrict__ bias,
                                                      void* __restrict__ Cout,
                                                      __bf16* __restrict__ Vt,
                                                      int M, int N, int K) {
    __shared__ __bf16 As[128 * 32];
    __shared__ __bf16 Bs[128 * 32];

    const int t = threadIdx.x;
    const int lane = t & 63;
    const int wave = t >> 6;
    const int wm = wave & 1, wn = wave >> 1;
    const int l15 = lane & 15;
    const int kg = (lane >> 4) * 8;

    const int m0 = blockIdx.y * 128;
    const int n0 = blockIdx.x * 128;

    const int srow = t >> 2;
    const int scol = (t & 3) * 8;
    const __bf16* ag = A  + (size_t)(m0 + srow) * K + scol;
    const __bf16* bg = BT + (size_t)(n0 + srow) * K + scol;
    __bf16* al = As + t * 8;
    __bf16* bl = Bs + t * 8;

    floatx4 acc[4][4] = {};

    for (int k0 = 0; k0 < K; k0 += 32) {
        __syncthreads();
        async16(ag + k0,                    al);
        async16(ag + (size_t)64 * K + k0,   al + 2048);
        async16(bg + k0,                    bl);
        async16(bg + (size_t)64 * K + k0,   bl + 2048);
        __syncthreads();

        bf16x8 af[4], bfr[4];
#pragma unroll
        for (int mi = 0; mi < 4; ++mi)
            af[mi] = *(const bf16x8*)(As + (wm * 64 + mi * 16 + l15) * 32 + kg);
#pragma unroll
        for (int ni = 0; ni < 4; ++ni)
            bfr[ni] = *(const bf16x8*)(Bs + (wn * 64 + ni * 16 + l15) * 32 + kg);
#pragma unroll
        for (int mi = 0; mi < 4; ++mi)
#pragma unroll
            for (int ni = 0; ni < 4; ++ni)
                acc[mi][ni] = MFMA16(af[mi], bfr[ni], acc[mi][ni]);
    }

    // C/D layout: col = lane&15, row = (lane>>4)*4 + reg   [verified m89/m91]
    const int r0 = (lane >> 4) * 4;
    const int wn0 = n0 + wn * 64;

    if (MODE == 2 && (wn0 % 192) == 128) {
        // v-chunk -> Vt[b][h][d][s] (pitch VP); 4 consecutive rows = 8B store
#pragma unroll
        for (int ni = 0; ni < 4; ++ni) {
            int col = wn0 + ni * 16 + l15;
            float bv = bias[col];
            int h = col / 192;
            int d = col - h * 192 - 128;
#pragma unroll
            for (int mi = 0; mi < 4; ++mi) {
                int row = m0 + wm * 64 + mi * 16 + r0;
                int b = row >> 11, s = row & 2047;
                bf16x4 vv;
#pragma unroll
                for (int i = 0; i < 4; ++i) vv[i] = (__bf16)(acc[mi][ni][i] + bv);
                *(bf16x4*)(Vt + ((size_t)(b * Hq + h) * HDq + d) * VP + s) = vv;
            }
        }
    } else {
        // wave-uniform q-scale for MODE 2 q-chunks (wn0%192==0)
        const float sc = (MODE == 2 && (wn0 % 192) == 0) ? QSCALE : 1.0f;
#pragma unroll
        for (int ni = 0; ni < 4; ++ni) {
            int col = wn0 + ni * 16 + l15;
            float bv = bias[col];
#pragma unroll
            for (int mi = 0; mi < 4; ++mi) {
#pragma unroll
                for (int i = 0; i < 4; ++i) {
                    int row = m0 + wm * 64 + mi * 16 + r0 + i;
                    float v = (acc[mi][ni][i] + bv) * sc;
                    size_t off = (size_t)row * N + col;
                    if (MODE == 1) ((float*)Cout)[off] = v;
                    else           ((__bf16*)Cout)[off] = (__bf16)v;
                }
            }
        }
    }
}

// ---------------------------------------------------------------------------
// Flash attention, transposed compute (S^T = K Q^T, O^T = V^T P^T), max-free
// softmax (q pre-scaled by 0.125*log2e -> p = exp2(s) one v_exp_f32).
// NO K/V LDS staging: K A-frags read straight from qkv (row stride 6144 B,
// non-pow2 -> L1-friendly); V A-frags from Vt (pitch 4224 B = 33 lines).
// The 4 waves of a block read identical K/V lines -> L1/L2 dedupe.
// Only wave-private P^T roundtrip uses LDS; NO barriers in the K-loop.
__global__ __launch_bounds__(256, 4) void attn_kernel(const __bf16* __restrict__ qkv,
                                                      const __bf16* __restrict__ Vt,
                                                      __bf16* __restrict__ v2) {
    const int bh = blockIdx.y;
    const int b = bh >> 4, h = bh & 15;
    const int q0 = blockIdx.x * 128;
    const int lane = threadIdx.x & 63;
    const int wave = threadIdx.x >> 6;
    const int l15 = lane & 15;
    const int quad = lane >> 4;
    const int kg = quad * 8;
    const size_t rs = QKV_N;
    const __bf16* base  = qkv + (size_t)b * Sq * rs + (size_t)h * (3 * HDq);
    const __bf16* vbase = Vt + (size_t)bh * HDq * VP;

    __shared__ alignas(16) __bf16 PT[4][2][16][72];  // [wave][qt][q=l15][key]

    // Q fragments (QSCALE pre-folded by GEMM1); B-frag layout == A-frag layout.
    bf16x8 qa[2][2];
#pragma unroll
    for (int qt = 0; qt < 2; ++qt) {
        const __bf16* qr = base + (size_t)(q0 + qt * 64 + wave * 16 + l15) * rs;
        qa[qt][0] = *(const bf16x8*)(qr + kg);
        qa[qt][1] = *(const bf16x8*)(qr + 32 + kg);
    }

    // Per-lane K/V row pointers (advance in-loop; contiguous 16B frag loads).
    const __bf16* kp[4];
    const __bf16* vp[4];
#pragma unroll
    for (int tt = 0; tt < 4; ++tt) {
        kp[tt] = base + HDq + (size_t)(tt * 16 + l15) * rs + kg;   // K rows
        vp[tt] = vbase + (size_t)(tt * 16 + l15) * VP + kg;        // V^T rows
    }

    floatx4 o[2][4] = {};   // O^T tiles: rows d = tt*16+quad*4+i, col q = l15
    float l_acc[2] = {0.f, 0.f};

    for (int kt = 0; kt < Sq; kt += 64) {
        // K fragment loads (8x b128, L1/L2-served, shared across waves)
        bf16x8 ka0[4], ka1[4];
#pragma unroll
        for (int tt = 0; tt < 4; ++tt) {
            ka0[tt] = *(const bf16x8*)(kp[tt]);
            ka1[tt] = *(const bf16x8*)(kp[tt] + 32);
            kp[tt] += (size_t)64 * rs;
        }
        // V fragment loads (8x b128) — issued early, consumed after softmax
        bf16x8 va0[4], va1[4];
#pragma unroll
        for (int tt = 0; tt < 4; ++tt) {
            va0[tt] = *(const bf16x8*)(vp[tt]);
            va1[tt] = *(const bf16x8*)(vp[tt] + 32);
            vp[tt] += 64;
        }

        // S^T = K Q^T  (A = K rows, B = Q^T)
        floatx4 s[2][4];
#pragma unroll
        for (int tt = 0; tt < 4; ++tt) {
#pragma unroll
            for (int qt = 0; qt < 2; ++qt) {
                floatx4 z = {};
                z = MFMA16(ka0[tt], qa[qt][0], z);
                s[qt][tt] = MFMA16(ka1[tt], qa[qt][1], z);
            }
        }

        // exp2 + vectorized P^T store (wave-private rows: no barrier)
#pragma unroll
        for (int qt = 0; qt < 2; ++qt) {
            float lsum = 0.f;
#pragma unroll
            for (int tt = 0; tt < 4; ++tt) {
                bf16x4 pp;
#pragma unroll
                for (int i = 0; i < 4; ++i) {
                    float p = __builtin_amdgcn_exp2f(s[qt][tt][i]);
                    lsum += p;
                    pp[i] = (__bf16)p;
                }
                *(bf16x4*)(&PT[wave][qt][l15][tt * 16 + quad * 4]) = pp;
            }
            l_acc[qt] += lsum;
        }

        // O^T += V^T P^T  (A = V^T rows in regs, B = P^T rows from LDS)
#pragma unroll
        for (int qt = 0; qt < 2; ++qt) {
            bf16x8 pa0 = *(const bf16x8*)(&PT[wave][qt][l15][kg]);
            bf16x8 pa1 = *(const bf16x8*)(&PT[wave][qt][l15][32 + kg]);
#pragma unroll
            for (int tt = 0; tt < 4; ++tt) {
                o[qt][tt] = MFMA16(va0[tt], pa0, o[qt][tt]);
                o[qt][tt] = MFMA16(va1[tt], pa1, o[qt][tt]);
            }
        }
    }

    // l reduction across the 4 quads holding the same q (=l15)
    float rinv[2];
#pragma unroll
    for (int qt = 0; qt < 2; ++qt) {
        float l = l_acc[qt];
        l += __shfl_xor(l, 16);
        l += __shfl_xor(l, 32);
        rinv[qt] = 1.0f / l;
    }

    // Epilogue: O^T lane holds fixed q=l15, 4 consecutive d -> 8B stores.
    // Quirk reshape: v2[b*2048 + h*128 + q/16][(q%16)*64 + d]
#pragma unroll
    for (int qt = 0; qt < 2; ++qt) {
        int q = q0 + qt * 64 + wave * 16 + l15;
        size_t row = (size_t)b * Sq + h * 128 + (q >> 4);
        __bf16* vrow = v2 + row * Dq + (size_t)(q & 15) * 64;
#pragma unroll
        for (int tt = 0; tt < 4; ++tt) {
            bf16x4 ov;
#pragma unroll
            for (int i = 0; i < 4; ++i)
                ov[i] = (__bf16)(o[qt][tt][i] * rinv[qt]);
            *(bf16x4*)(vrow + tt * 16 + quad * 4) = ov;
        }
    }
}

// ---------------------------------------------------------------------------
extern "C" void kernel_launch(void* const* d_in, const int* in_sizes, int n_in,
                              void* d_out, int out_size, void* d_ws, size_t ws_size,
                              hipStream_t stream) {
    const float* x    = (const float*)d_in[0];  // [4,2048,1024]
    const float* Wqkv = (const float*)d_in[1];  // [1024,3072]
    const float* bqkv = (const float*)d_in[2];  // [3072]
    const float* Wo   = (const float*)d_in[3];  // [1024,1024]
    const float* bo   = (const float*)d_in[4];  // [1024]
    float* out = (float*)d_out;                 // [4,2048,1024] f32

    __bf16* xb    = (__bf16*)d_ws;                        // 8192*1024
    __bf16* WqkvT = xb    + (size_t)ROWS * Dq;            // 3072*1024
    __bf16* WoT   = WqkvT + (size_t)QKV_N * Dq;           // 1024*1024
    __bf16* qkvb  = WoT   + (size_t)Dq * Dq;              // 8192*3072
    __bf16* Vt    = qkvb  + (size_t)ROWS * QKV_N;         // 64*64*VP
    __bf16* v2    = xb;                                   // alias (xb dead)

    const int nx4 = ROWS * Dq / 4;
    cvt4_kernel<<<(nx4 + 255) / 256, 256, 0, stream>>>((const float4*)x, (bf16x4*)xb, nx4);
    tcvt_kernel<<<dim3(QKV_N / 32, Dq / 32), 256, 0, stream>>>(Wqkv, WqkvT, Dq, QKV_N);
    tcvt_kernel<<<dim3(Dq / 32, Dq / 32), 256, 0, stream>>>(Wo, WoT, Dq, Dq);

    gemm_bt_kernel<2><<<dim3(QKV_N / 128, ROWS / 128), 256, 0, stream>>>(
        xb, WqkvT, bqkv, (void*)qkvb, Vt, ROWS, QKV_N, Dq);

    attn_kernel<<<dim3(Sq / 128, Bq * Hq), 256, 0, stream>>>(qkvb, Vt, v2);

    gemm_bt_kernel<1><<<dim3(Dq / 128, ROWS / 128), 256, 0, stream>>>(
        v2, WoT, bo, (void*)out, nullptr, ROWS, Dq, Dq);
}

// Round 7
// 313.447 us; speedup vs baseline: 1.4381x; 1.4381x over previous
//
#include <hip/hip_runtime.h>
#include <hip/hip_bf16.h>
#include <cstdint>

// Problem constants: B=4, S=2048, D=1024, H=16, HD=64
static constexpr int Bq  = 4;
static constexpr int Sq  = 2048;
static constexpr int Dq  = 1024;
static constexpr int Hq  = 16;
static constexpr int HDq = 64;
static constexpr int ROWS = Bq * Sq;        // 8192
static constexpr int QKV_N = 3 * Dq;        // 3072
static constexpr int VP   = 2112;           // Vt pitch (el): 4224 B, non-pow2

typedef __bf16 bf16x8 __attribute__((ext_vector_type(8)));
typedef __bf16 bf16x4 __attribute__((ext_vector_type(4)));
typedef float  floatx4 __attribute__((ext_vector_type(4)));

#define MFMA16(a, b, c) __builtin_amdgcn_mfma_f32_16x16x32_bf16((a), (b), (c), 0, 0, 0)

// 0.125 (1/sqrt(HD)) * log2(e): folded into q so softmax uses exp2 directly.
#define QSCALE 0.18033688011112042f

// Async global->LDS 16B copy (global_load_lds_dwordx4).
__device__ __forceinline__ void async16(const void* g, void* l) {
    __builtin_amdgcn_global_load_lds(
        (const __attribute__((address_space(1))) uint32_t*)g,
        (__attribute__((address_space(3))) uint32_t*)l, 16, 0, 0);
}

// ---------------------------------------------------------------------------
// fp32 -> bf16 elementwise convert, 4 elems/thread
__global__ __launch_bounds__(256) void cvt4_kernel(const float4* __restrict__ in,
                                                   bf16x4* __restrict__ out, int n4) {
    int i = blockIdx.x * 256 + threadIdx.x;
    if (i < n4) {
        float4 v = in[i];
        bf16x4 o;
        o[0] = (__bf16)v.x; o[1] = (__bf16)v.y; o[2] = (__bf16)v.z; o[3] = (__bf16)v.w;
        out[i] = o;
    }
}

// fp32 [K,N] -> bf16 transposed [N,K], LDS-tiled 32x32 for coalescing
__global__ __launch_bounds__(256) void tcvt_kernel(const float* __restrict__ in,
                                                   __bf16* __restrict__ out, int K, int N) {
    __shared__ float t[32][33];
    int n0 = blockIdx.x * 32, k0 = blockIdx.y * 32;
    int c = threadIdx.x & 31, r0 = threadIdx.x >> 5;
#pragma unroll
    for (int rr = 0; rr < 32; rr += 8)
        t[r0 + rr][c] = in[(size_t)(k0 + r0 + rr) * N + n0 + c];
    __syncthreads();
#pragma unroll
    for (int rr = 0; rr < 32; rr += 8)
        out[(size_t)(n0 + r0 + rr) * K + k0 + c] = (__bf16)t[c][r0 + rr];
}

// ---------------------------------------------------------------------------
// C[M,N] = A[M,K] @ BT[N,K]^T + bias[N]  (m97-ladder structure).
// MODE 1: f32 C out.  MODE 2 (QKV): q-chunks scaled by QSCALE -> bf16 C;
// k-chunks -> bf16 C; v-chunks -> transposed Vt[b][h][d][s] with pitch VP.
template <int MODE>
__global__ __launch_bounds__(256) void gemm_bt_kernel(const __bf16* __restrict__ A,
                                                      const __bf16* __restrict__ BT,
                                                      const float* __restrict__ bias,
                                                      void* __restrict__ Cout,
                                                      __bf16* __restrict__ Vt,
                                                      int M, int N, int K) {
    __shared__ __bf16 As[128 * 32];
    __shared__ __bf16 Bs[128 * 32];

    const int t = threadIdx.x;
    const int lane = t & 63;
    const int wave = t >> 6;
    const int wm = wave & 1, wn = wave >> 1;
    const int l15 = lane & 15;
    const int kg = (lane >> 4) * 8;

    const int m0 = blockIdx.y * 128;
    const int n0 = blockIdx.x * 128;

    const int srow = t >> 2;
    const int scol = (t & 3) * 8;
    const __bf16* ag = A  + (size_t)(m0 + srow) * K + scol;
    const __bf16* bg = BT + (size_t)(n0 + srow) * K + scol;
    __bf16* al = As + t * 8;
    __bf16* bl = Bs + t * 8;

    floatx4 acc[4][4] = {};

    for (int k0 = 0; k0 < K; k0 += 32) {
        __syncthreads();
        async16(ag + k0,                    al);
        async16(ag + (size_t)64 * K + k0,   al + 2048);
        async16(bg + k0,                    bl);
        async16(bg + (size_t)64 * K + k0,   bl + 2048);
        __syncthreads();

        bf16x8 af[4], bfr[4];
#pragma unroll
        for (int mi = 0; mi < 4; ++mi)
            af[mi] = *(const bf16x8*)(As + (wm * 64 + mi * 16 + l15) * 32 + kg);
#pragma unroll
        for (int ni = 0; ni < 4; ++ni)
            bfr[ni] = *(const bf16x8*)(Bs + (wn * 64 + ni * 16 + l15) * 32 + kg);
#pragma unroll
        for (int mi = 0; mi < 4; ++mi)
#pragma unroll
            for (int ni = 0; ni < 4; ++ni)
                acc[mi][ni] = MFMA16(af[mi], bfr[ni], acc[mi][ni]);
    }

    // C/D layout: col = lane&15, row = (lane>>4)*4 + reg   [verified m89/m91]
    const int r0 = (lane >> 4) * 4;
    const int wn0 = n0 + wn * 64;

    if (MODE == 2 && (wn0 % 192) == 128) {
        // v-chunk -> Vt[b][h][d][s] (pitch VP); 4 consecutive rows = 8B store
#pragma unroll
        for (int ni = 0; ni < 4; ++ni) {
            int col = wn0 + ni * 16 + l15;
            float bv = bias[col];
            int h = col / 192;
            int d = col - h * 192 - 128;
#pragma unroll
            for (int mi = 0; mi < 4; ++mi) {
                int row = m0 + wm * 64 + mi * 16 + r0;
                int b = row >> 11, s = row & 2047;
                bf16x4 vv;
#pragma unroll
                for (int i = 0; i < 4; ++i) vv[i] = (__bf16)(acc[mi][ni][i] + bv);
                *(bf16x4*)(Vt + ((size_t)(b * Hq + h) * HDq + d) * VP + s) = vv;
            }
        }
    } else {
        // wave-uniform q-scale for MODE 2 q-chunks (wn0%192==0)
        const float sc = (MODE == 2 && (wn0 % 192) == 0) ? QSCALE : 1.0f;
#pragma unroll
        for (int ni = 0; ni < 4; ++ni) {
            int col = wn0 + ni * 16 + l15;
            float bv = bias[col];
#pragma unroll
            for (int mi = 0; mi < 4; ++mi) {
#pragma unroll
                for (int i = 0; i < 4; ++i) {
                    int row = m0 + wm * 64 + mi * 16 + r0 + i;
                    float v = (acc[mi][ni][i] + bv) * sc;
                    size_t off = (size_t)row * N + col;
                    if (MODE == 1) ((float*)Cout)[off] = v;
                    else           ((__bf16*)Cout)[off] = (__bf16)v;
                }
            }
        }
    }
}

// ---------------------------------------------------------------------------
// Flash attention, transposed compute (S^T = K Q^T, O^T = V^T P^T), max-free
// softmax (q pre-scaled by 0.125*log2e -> p = exp2(s) one v_exp_f32).
// Block = one (b,h) x 256 q-rows (qt=0..3); 4 waves; wave owns q rows
// {qt*64 + wave*16 .. +16}. K/V double-buffered in LDS (ONE barrier/iter),
// register-prefetch pipeline; the per-block K/V LDS frag reads amortize over
// 2x the q-rows vs the 128-row tile (LDS pipe was the round-5 bottleneck).
// Wave-private P^T roundtrip in LDS (pad-72 rows, b64 writes / b128 reads).
__global__ __launch_bounds__(256) void attn_kernel(const __bf16* __restrict__ qkv,
                                                   const __bf16* __restrict__ Vt,
                                                   __bf16* __restrict__ v2) {
    const int bh = blockIdx.y;
    const int b = bh >> 4, h = bh & 15;
    const int q0 = blockIdx.x * 256;
    const int tid = threadIdx.x;
    const int lane = tid & 63;
    const int wave = tid >> 6;
    const int l15 = lane & 15;
    const int quad = lane >> 4;
    const int kg = quad * 8;
    const size_t rs = QKV_N;
    const __bf16* base  = qkv + (size_t)b * Sq * rs + (size_t)h * (3 * HDq);
    const __bf16* vbase = Vt + (size_t)bh * HDq * VP;

    __shared__ alignas(16) __bf16 Ks[2][64][72];   // [buf][key][d]
    __shared__ alignas(16) __bf16 Vs[2][64][72];   // [buf][d][key]
    __shared__ alignas(16) __bf16 PT[4][4][16][72];// [wave][qt][q=l15][key]

    // Q fragments (QSCALE pre-folded by GEMM1); B-frag layout == A-frag layout.
    bf16x8 qa[4][2];
#pragma unroll
    for (int qt = 0; qt < 4; ++qt) {
        const __bf16* qr = base + (size_t)(q0 + qt * 64 + wave * 16 + l15) * rs;
        qa[qt][0] = *(const bf16x8*)(qr + kg);
        qa[qt][1] = *(const bf16x8*)(qr + 32 + kg);
    }

    // staging map: thread -> (row sd, 16B chunk sc) of the 64x64 tile
    const int sd = tid >> 2;            // 0..63
    const int sc = (tid & 3) * 8;       // el offset: 0,8,16,24 (+32 2nd chunk)
    const __bf16* kgp = base + 64 + (size_t)sd * rs + sc;
    const __bf16* vgp = vbase + (size_t)sd * VP + sc;

    bf16x8 kr0 = *(const bf16x8*)(kgp);
    bf16x8 kr1 = *(const bf16x8*)(kgp + 32);
    bf16x8 vr0 = *(const bf16x8*)(vgp);
    bf16x8 vr1 = *(const bf16x8*)(vgp + 32);

    floatx4 o[4][4] = {};   // O^T tiles: rows d = tt*16+quad*4+i, col q = l15
    float l_acc[4] = {};

    for (int kt = 0; kt < Sq; kt += 64) {
        const int buf = (kt >> 6) & 1;
        // write prefetched tile into this iteration's buffer
        *(bf16x8*)(&Ks[buf][sd][sc])      = kr0;
        *(bf16x8*)(&Ks[buf][sd][sc + 32]) = kr1;
        *(bf16x8*)(&Vs[buf][sd][sc])      = vr0;
        *(bf16x8*)(&Vs[buf][sd][sc + 32]) = vr1;
        __syncthreads();  // single barrier: tile visible; prev buf reads done
                          // (prev-iter reads used the other buffer)

        // global prefetch of next tile (wraps on last iter; harmless)
        const int ktn = (kt + 64) & (Sq - 1);
        kr0 = *(const bf16x8*)(kgp + (size_t)ktn * rs);
        kr1 = *(const bf16x8*)(kgp + (size_t)ktn * rs + 32);
        vr0 = *(const bf16x8*)(vgp + ktn);
        vr1 = *(const bf16x8*)(vgp + ktn + 32);

        // K fragments once, shared across all 4 q-subtiles
        bf16x8 ka0[4], ka1[4];
#pragma unroll
        for (int tt = 0; tt < 4; ++tt) {
            ka0[tt] = *(const bf16x8*)(&Ks[buf][tt * 16 + l15][kg]);
            ka1[tt] = *(const bf16x8*)(&Ks[buf][tt * 16 + l15][32 + kg]);
        }

        // S^T = K Q^T ; exp2 ; vectorized P^T store (wave-private rows)
#pragma unroll
        for (int qt = 0; qt < 4; ++qt) {
            floatx4 s[4];
#pragma unroll
            for (int tt = 0; tt < 4; ++tt) {
                floatx4 z = {};
                z = MFMA16(ka0[tt], qa[qt][0], z);
                s[tt] = MFMA16(ka1[tt], qa[qt][1], z);
            }
            float lsum = 0.f;
#pragma unroll
            for (int tt = 0; tt < 4; ++tt) {
                bf16x4 pp;
#pragma unroll
                for (int i = 0; i < 4; ++i) {
                    float p = __builtin_amdgcn_exp2f(s[tt][i]);
                    lsum += p;
                    pp[i] = (__bf16)p;
                }
                *(bf16x4*)(&PT[wave][qt][l15][tt * 16 + quad * 4]) = pp;
            }
            l_acc[qt] += lsum;
        }

        // O^T += V^T P^T  (A = V^T rows from Vs, B = P^T rows from PT)
#pragma unroll
        for (int ks = 0; ks < 2; ++ks) {
            bf16x8 va[4];
#pragma unroll
            for (int tt = 0; tt < 4; ++tt)
                va[tt] = *(const bf16x8*)(&Vs[buf][tt * 16 + l15][ks * 32 + kg]);
#pragma unroll
            for (int qt = 0; qt < 4; ++qt) {
                bf16x8 pa = *(const bf16x8*)(&PT[wave][qt][l15][ks * 32 + kg]);
#pragma unroll
                for (int tt = 0; tt < 4; ++tt)
                    o[qt][tt] = MFMA16(va[tt], pa, o[qt][tt]);
            }
        }
    }

    // l reduction across the 4 quads holding the same q (=l15)
    float rinv[4];
#pragma unroll
    for (int qt = 0; qt < 4; ++qt) {
        float l = l_acc[qt];
        l += __shfl_xor(l, 16);
        l += __shfl_xor(l, 32);
        rinv[qt] = 1.0f / l;
    }

    // Epilogue: O^T lane holds fixed q=l15, 4 consecutive d -> 8B stores.
    // Quirk reshape: v2[b*2048 + h*128 + q/16][(q%16)*64 + d]
#pragma unroll
    for (int qt = 0; qt < 4; ++qt) {
        int q = q0 + qt * 64 + wave * 16 + l15;
        size_t row = (size_t)b * Sq + h * 128 + (q >> 4);
        __bf16* vrow = v2 + row * Dq + (size_t)(q & 15) * 64;
#pragma unroll
        for (int tt = 0; tt < 4; ++tt) {
            bf16x4 ov;
#pragma unroll
            for (int i = 0; i < 4; ++i)
                ov[i] = (__bf16)(o[qt][tt][i] * rinv[qt]);
            *(bf16x4*)(vrow + tt * 16 + quad * 4) = ov;
        }
    }
}

// ---------------------------------------------------------------------------
extern "C" void kernel_launch(void* const* d_in, const int* in_sizes, int n_in,
                              void* d_out, int out_size, void* d_ws, size_t ws_size,
                              hipStream_t stream) {
    const float* x    = (const float*)d_in[0];  // [4,2048,1024]
    const float* Wqkv = (const float*)d_in[1];  // [1024,3072]
    const float* bqkv = (const float*)d_in[2];  // [3072]
    const float* Wo   = (const float*)d_in[3];  // [1024,1024]
    const float* bo   = (const float*)d_in[4];  // [1024]
    float* out = (float*)d_out;                 // [4,2048,1024] f32

    __bf16* xb    = (__bf16*)d_ws;                        // 8192*1024
    __bf16* WqkvT = xb    + (size_t)ROWS * Dq;            // 3072*1024
    __bf16* WoT   = WqkvT + (size_t)QKV_N * Dq;           // 1024*1024
    __bf16* qkvb  = WoT   + (size_t)Dq * Dq;              // 8192*3072
    __bf16* Vt    = qkvb  + (size_t)ROWS * QKV_N;         // 64*64*VP
    __bf16* v2    = xb;                                   // alias (xb dead)

    const int nx4 = ROWS * Dq / 4;
    cvt4_kernel<<<(nx4 + 255) / 256, 256, 0, stream>>>((const float4*)x, (bf16x4*)xb, nx4);
    tcvt_kernel<<<dim3(QKV_N / 32, Dq / 32), 256, 0, stream>>>(Wqkv, WqkvT, Dq, QKV_N);
    tcvt_kernel<<<dim3(Dq / 32, Dq / 32), 256, 0, stream>>>(Wo, WoT, Dq, Dq);

    gemm_bt_kernel<2><<<dim3(QKV_N / 128, ROWS / 128), 256, 0, stream>>>(
        xb, WqkvT, bqkv, (void*)qkvb, Vt, ROWS, QKV_N, Dq);

    attn_kernel<<<dim3(Sq / 256, Bq * Hq), 256, 0, stream>>>(qkvb, Vt, v2);

    gemm_bt_kernel<1><<<dim3(Dq / 128, ROWS / 128), 256, 0, stream>>>(
        v2, WoT, bo, (void*)out, nullptr, ROWS, Dq, Dq);
}